// Round 7
// baseline (348.251 us; speedup 1.0000x reference)
//
#include <hip/hip_runtime.h>

#define HW 128
#define KTAPS 255
#define DIMC 256

typedef short short8  __attribute__((ext_vector_type(8)));
typedef short short4v __attribute__((ext_vector_type(4)));
typedef float f32x16  __attribute__((ext_vector_type(16)));
typedef float f32x4   __attribute__((ext_vector_type(4)));

__device__ __forceinline__ short f2bf(float f) {
    return __builtin_bit_cast(short, (__bf16)f);
}
// Padded chunk addressing: 16B chunk index -> 16B slot
__device__ __forceinline__ int pad16(int c) { return c + (c >> 3); }

// LDS-only barrier: does NOT drain vmcnt (global loads/stores stay in flight).
// The "memory" clobber also stops LICM from hoisting the per-slice weight
// gathers into registers (v4's 96-VGPR spill trap).
__device__ __forceinline__ void bar_lds() {
    asm volatile("s_waitcnt lgkmcnt(0)" ::: "memory");
    __builtin_amdgcn_s_barrier();
}

// 8 consecutive taps (4B-aligned only!) -> bf16 frag. memcpy keeps it legal
// for unaligned-16B; lowers to 2x global_load_dwordx4 align 4.
__device__ __forceinline__ short8 wfrag(const float* __restrict__ p) {
    float t[8];
    __builtin_memcpy(t, p, 32);
    short8 v;
#pragma unroll
    for (int j = 0; j < 8; ++j) v[j] = f2bf(t[j]);
    return v;
}

// Fragment layouts (v_mfma_f32_32x32x16_bf16):
//  A (MxK): elem(m,k): chunk=((m>>5)*8+(k>>4))*64 + (m&31)+32*((k>>3)&1), j=k&7
//  B (KxN): elem(k,n): chunk=((n>>5)*8+(k>>4))*64 + (n&31)+32*((k>>3)&1), j=k&7
//  C/D: col=lane&31, row=(reg&3)+8*(reg>>2)+4*(lane>>5)
//
// v8: 2 blocks/CU for cross-block HBM/LDS overlap (1-block versions serialize
//     the two pipes; measured = their sum). Commuted form kept (v7, verified):
//       Z = Ah*(X*Bw) + cw[w],  cw[w] = bh*sum_k Bw[k,w] + bw
//  - grid = 512: block (c, half) does 5 batch slices of channel c.
//  - 512 thr = 8 waves; wave (wm = wv>>1, wn in {wv&1, wv&1+2}) = 2 tiles.
//  - Weight frags gathered straight from global (L1-hot 1KB band) — no WB.
//  - No Zt: scalar stores are 128B-segment coalesced anyway.
//  - LDS: PxA 36K + Py 36K + cw 0.5K = 74 KB -> 2 blocks/CU.
//  - Per slice: 2 no-drain barriers; X prefetched 1 slice ahead in 32 VGPRs.

__global__ __launch_bounds__(512, 4)
void sep_conv255_mfma(const float* __restrict__ x,
                      const float* __restrict__ wh,
                      const float* __restrict__ bh,
                      const float* __restrict__ ww,
                      const float* __restrict__ bw,
                      float* __restrict__ out,
                      int nslices) {
    __shared__ __align__(16) short PxA[2304 * 8];  // X as mm1 A-frags (36 KB)
    __shared__ __align__(16) short Py [2304 * 8];  // W as mm2 B-frags (36 KB)
    __shared__ float cw[HW];                       // fused per-column bias

    const int c    = blockIdx.x >> 1;
    const int half = blockIdx.x & 1;
    const int tid  = threadIdx.x;       // 0..511
    const int lane = tid & 63;
    const int wv   = tid >> 6;          // 0..7
    const int wm   = wv >> 1;           // row-tile 0..3
    const int wn0  = wv & 1;            // col-tiles wn0, wn0+2
    const int s31  = lane & 31;
    const int hi   = lane >> 5;

    const int ns2  = (nslices + 1) >> 1;
    const int sbeg = half * ns2;
    const int cnt  = min(ns2, nslices - sbeg);
    if (cnt <= 0) return;

    const float* __restrict__ whc = wh + c * KTAPS;
    const float* __restrict__ wwc = ww + c * KTAPS;

    // X staging geometry: thread owns cols 4tw..4tw+3, rows g+16i (i=0..7)
    const int tw = tid & 31;
    const int g  = tid >> 5;            // 0..15
    const size_t ldOff = (size_t)g * HW + (tw << 2);
    int stChunk[8];
#pragma unroll
    for (int i = 0; i < 8; ++i) {
        const int r = g + (i << 4);
        stChunk[i] = (((r >> 5) << 3) + (tw >> 2)) * 64 + (r & 31) + (((tw >> 1) & 1) << 5);
    }
    const int stOff = (tw & 1) << 2;    // short offset within 16B chunk

    // ---------------- prologue ----------------
    f32x4 xv[8];
    {
        const float* xs = x + ((size_t)sbeg * DIMC + c) * (HW * HW);
#pragma unroll
        for (int i = 0; i < 8; ++i)
            xv[i] = *reinterpret_cast<const f32x4*>(&xs[ldOff + (size_t)(i << 4) * HW]);
    }
    // fused bias: cw[w] = bh * sum_k ww[127+k-w] + bw
    if (tid < HW) {
        float ssum = 0.0f;
        for (int i = 0; i < HW; ++i) ssum += wwc[127 - tid + i];
        cw[tid] = bh[c] * ssum + bw[c];
    }
    // stage slice-0 X
#pragma unroll
    for (int i = 0; i < 8; ++i) {
        short4v v;
#pragma unroll
        for (int j = 0; j < 4; ++j) v[j] = f2bf(xv[i][j]);
        *reinterpret_cast<short4v*>(&PxA[pad16(stChunk[i]) * 8 + stOff]) = v;
    }
    // issue slice-1 loads
    if (cnt > 1) {
        const float* xs = x + ((size_t)(sbeg + 1) * DIMC + c) * (HW * HW);
#pragma unroll
        for (int i = 0; i < 8; ++i)
            xv[i] = *reinterpret_cast<const f32x4*>(&xs[ldOff + (size_t)(i << 4) * HW]);
    }
    bar_lds();

    const float cwv0 = cw[(wn0 << 5) + s31];
    const float cwv1 = cw[((wn0 + 2) << 5) + s31];

    // Toeplitz gather bases: elem idx = 127 + 16ks + 8hi + j - 32*tile - s31 (in [0,254])
    const float* pb0 = wwc + (127 + (hi << 3) - s31 - (wn0 << 5));  // mm1 B; tile tt: -64*tt
    const float* pa0 = whc + (127 + (hi << 3) - s31 - (wm  << 5));  // mm2 A

    // ---------------- pipelined slice loop ----------------
    for (int s = 0; s < cnt; ++s) {
        // mm1: W = X * Bw  (A = X frags from LDS, B = weights from global/L1)
        f32x16 acc0, acc1;
#pragma unroll
        for (int j = 0; j < 16; ++j) { acc0[j] = 0.0f; acc1[j] = 0.0f; }
#pragma unroll
        for (int ks = 0; ks < 8; ++ks) {
            const short8 a = *reinterpret_cast<const short8*>(
                &PxA[pad16(((wm << 3) + ks) * 64 + lane) * 8]);
            const short8 b0 = wfrag(pb0 + (ks << 4));
            const short8 b1 = wfrag(pb0 + (ks << 4) - 64);
            acc0 = __builtin_amdgcn_mfma_f32_32x32x16_bf16(a, b0, acc0, 0, 0, 0);
            acc1 = __builtin_amdgcn_mfma_f32_32x32x16_bf16(a, b1, acc1, 0, 0, 0);
        }

        // repack W -> Py as mm2 B-frags (4 values per ds_write_b64)
        {
#pragma unroll
            for (int q = 0; q < 4; ++q) {
                const int chunk0 = ((wn0 << 3) + (wm << 1) + (q >> 1)) * 64 + s31 + ((q & 1) << 5);
                short4v v;
#pragma unroll
                for (int j = 0; j < 4; ++j) v[j] = f2bf(acc0[(q << 2) + j]);
                *reinterpret_cast<short4v*>(&Py[pad16(chunk0) * 8 + (hi << 2)]) = v;
            }
#pragma unroll
            for (int q = 0; q < 4; ++q) {
                const int chunk1 = (((wn0 + 2) << 3) + (wm << 1) + (q >> 1)) * 64 + s31 + ((q & 1) << 5);
                short4v v;
#pragma unroll
                for (int j = 0; j < 4; ++j) v[j] = f2bf(acc1[(q << 2) + j]);
                *reinterpret_cast<short4v*>(&Py[pad16(chunk1) * 8 + (hi << 2)]) = v;
            }
        }
        bar_lds();   // A: PxA reads retired; Py visible

        // stage X(s+1); issue loads X(s+2)
        if (s + 1 < cnt) {
#pragma unroll
            for (int i = 0; i < 8; ++i) {
                short4v v;
#pragma unroll
                for (int j = 0; j < 4; ++j) v[j] = f2bf(xv[i][j]);
                *reinterpret_cast<short4v*>(&PxA[pad16(stChunk[i]) * 8 + stOff]) = v;
            }
        }
        if (s + 2 < cnt) {
            const float* xs = x + ((size_t)(sbeg + s + 2) * DIMC + c) * (HW * HW);
#pragma unroll
            for (int i = 0; i < 8; ++i)
                xv[i] = *reinterpret_cast<const f32x4*>(&xs[ldOff + (size_t)(i << 4) * HW]);
        }

        // mm2: Z = Ah * W  (A = weights from global/L1, B = W frags from LDS)
#pragma unroll
        for (int j = 0; j < 16; ++j) { acc0[j] = 0.0f; acc1[j] = 0.0f; }
#pragma unroll
        for (int ks = 0; ks < 8; ++ks) {
            const short8 aw = wfrag(pa0 + (ks << 4));
            const short8 B0 = *reinterpret_cast<const short8*>(
                &Py[pad16(((wn0 << 3) + ks) * 64 + lane) * 8]);
            const short8 B1 = *reinterpret_cast<const short8*>(
                &Py[pad16((((wn0 + 2) << 3) + ks) * 64 + lane) * 8]);
            acc0 = __builtin_amdgcn_mfma_f32_32x32x16_bf16(aw, B0, acc0, 0, 0, 0);
            acc1 = __builtin_amdgcn_mfma_f32_32x32x16_bf16(aw, B1, acc1, 0, 0, 0);
        }

        // stores: coalesced 128B segments, fire-and-forget
        {
            float* zc = out + ((size_t)(sbeg + s) * DIMC + c) * (HW * HW);
            const int w0 = (wn0 << 5) + s31;
            const int hb = (wm << 5) + (hi << 2);
#pragma unroll
            for (int r = 0; r < 16; ++r) {
                const int h = hb + (r & 3) + ((r >> 2) << 3);
                zc[(size_t)h * HW + w0]      = acc0[r] + cwv0;
                zc[(size_t)h * HW + w0 + 64] = acc1[r] + cwv1;
            }
        }
        bar_lds();   // B: Py reads retired; PxA(s+1) visible
    }
}

extern "C" void kernel_launch(void* const* d_in, const int* in_sizes, int n_in,
                              void* d_out, int out_size, void* d_ws, size_t ws_size,
                              hipStream_t stream) {
    const float* x  = (const float*)d_in[0];
    const float* wh = (const float*)d_in[1];
    const float* bh = (const float*)d_in[2];
    const float* ww = (const float*)d_in[3];
    const float* bw = (const float*)d_in[4];
    float* outp = (float*)d_out;

    const int nbatch = in_sizes[0] / (DIMC * HW * HW);  // = 10
    dim3 grid(DIMC * 2);
    dim3 block(512);
    hipLaunchKernelGGL(sep_conv255_mfma, grid, block, 0, stream,
                       x, wh, bh, ww, bw, outp, nbatch);
}

// Round 8
// 291.284 us; speedup vs baseline: 1.1956x; 1.1956x over previous
//
#include <hip/hip_runtime.h>

#define HW 128
#define KTAPS 255
#define DIMC 256

typedef short short8  __attribute__((ext_vector_type(8)));
typedef short short4v __attribute__((ext_vector_type(4)));
typedef float f32x16  __attribute__((ext_vector_type(16)));
typedef float f32x4   __attribute__((ext_vector_type(4)));

__device__ __forceinline__ short f2bf(float f) {
    return __builtin_bit_cast(short, (__bf16)f);
}
// Padded chunk addressing: 16B chunk index -> 16B slot
__device__ __forceinline__ int pad16(int c) { return c + (c >> 3); }

// LDS-only barrier: does NOT drain vmcnt (global loads/stores stay in flight)
__device__ __forceinline__ void bar_lds() {
    asm volatile("s_waitcnt lgkmcnt(0)" ::: "memory");
    __builtin_amdgcn_s_barrier();
}

// Fragment layouts (v_mfma_f32_32x32x16_bf16):
//  A (MxK): elem(m,k): chunk=((m>>5)*8+(k>>4))*64 + (m&31)+32*((k>>3)&1), j=k&7
//  B (KxN): elem(k,n): chunk=((n>>5)*8+(k>>4))*64 + (n&31)+32*((k>>3)&1), j=k&7
//  C/D: col=lane&31, row=(reg&3)+8*(reg>>2)+4*(lane>>5)
//
// v9: v7's proven pipeline (commuted convs, WB built once, 1-slice prefetch,
//     no-drain barriers) split into TWO blocks per channel along output
//     columns -> 2 blocks/CU (the latency/lockstep gaps of one block overlap
//     the other's). No per-slice global weight gathers (v8's L1 mistake), no
//     memcpy/local arrays (v8's spill trigger).
//       Z = Ah*(X*Bw) + cw[w],  cw[w] = bh*sum_k Bw[k,w] + bw
//     Block (c, half): w-cols [64*half, 64*half+64) of all 10 slices.
//     mm1: W = X*Bw (full h, half w)  mm2: Z = Ah*W (reduction h' block-local)
//     LDS: PxA 36K (full X) + Py 18K (half W) + WB 24K (14 Ah + 10 Bw tiles)
//          + cw 256B = 80,128 B -> exactly 2 blocks/CU.
//     512 thr = 8 waves: wave (wm = wv>>1, l = wv&1) -> one 32x32 tile per mm.

__global__ __launch_bounds__(512, 4)
void sep_conv255_mfma(const float* __restrict__ x,
                      const float* __restrict__ wh,
                      const float* __restrict__ bh,
                      const float* __restrict__ ww,
                      const float* __restrict__ bw,
                      float* __restrict__ out,
                      int nslices) {
    __shared__ __align__(16) short PxA[2304 * 8];  // X as mm1 A-frags (36 KB)
    __shared__ __align__(16) short Py [1152 * 8];  // W-half as mm2 B-frags (18 KB)
    __shared__ __align__(16) short WB [1536 * 8];  // tiles 0..13 Ah, 14..23 Bw (24 KB)
    __shared__ float cw[64];                       // fused per-column bias (256 B)

    const int c    = blockIdx.x >> 1;   // channel
    const int half = blockIdx.x & 1;    // w-half: cols 64*half ..+63
    const int tid  = threadIdx.x;       // 0..511
    const int lane = tid & 63;
    const int wv   = tid >> 6;          // 0..7
    const int wm   = wv >> 1;           // row-tile 0..3 (h)
    const int l    = wv & 1;            // local col-tile 0..1
    const int s31  = lane & 31;
    const int hi   = lane >> 5;

    const float* __restrict__ whc = wh + c * KTAPS;
    const float* __restrict__ wwc = ww + c * KTAPS;
    const int bwlo = half ? 0 : 4;      // lowest Bw tile this half needs

    // X staging geometry: thread owns cols 4tw..4tw+3, rows g+16i (i=0..7)
    const int tw = tid & 31;
    const int g  = tid >> 5;            // 0..15
    const size_t ldOff = (size_t)g * HW + (tw << 2);
    int stChunk[8];
#pragma unroll
    for (int i = 0; i < 8; ++i) {
        const int r = g + (i << 4);
        stChunk[i] = (((r >> 5) << 3) + (tw >> 2)) * 64 + (r & 31) + (((tw >> 1) & 1) << 5);
    }
    const int stOff = (tw & 1) << 2;    // short offset within 16B chunk

    // ---------------- prologue ----------------
    f32x4 xv[8];
    {   // slice-0 loads first (hide under WB/cw build)
        const float* xs = x + (size_t)c * (HW * HW);
#pragma unroll
        for (int i = 0; i < 8; ++i)
            xv[i] = *reinterpret_cast<const f32x4*>(&xs[ldOff + (size_t)(i << 4) * HW]);
    }
    // WB build: 24 tiles x 64 chunks = 1536. tile<14: Ah t=tile; else Bw t=tile-14+bwlo.
    // lane lc of tile t: elem j = taps[31 + 16t + 8*(lc>>5) - (lc&31) + j]  (in [0,254])
#pragma unroll
    for (int i = 0; i < 3; ++i) {
        const int ch   = tid + (i << 9);          // 0..1535
        const int tile = ch >> 6;
        const int lc   = ch & 63;
        const bool isB = (tile >= 14);
        const int  t   = isB ? (tile - 14 + bwlo) : tile;
        const float* wsrc = isB ? wwc : whc;
        const float* wp = wsrc + (31 + (t << 4) + ((lc >> 5) << 3) - (lc & 31));
        short8 v;
#pragma unroll
        for (int j = 0; j < 8; ++j) v[j] = f2bf(wp[j]);
        *reinterpret_cast<short8*>(&WB[ch * 8]) = v;
    }
    // fused bias for this half's 64 columns: cw[i] = bh*sum_k ww[127+k-w] + bw
    if (tid < 64) {
        const int w = (half << 6) + tid;
        float ssum = 0.0f;
        for (int k = 0; k < HW; ++k) ssum += wwc[127 + k - w];
        cw[tid] = bh[c] * ssum + bw[c];
    }
    // stage slice-0 X (compiler inserts counted vmcnt on xv)
#pragma unroll
    for (int i = 0; i < 8; ++i) {
        short4v v;
#pragma unroll
        for (int j = 0; j < 4; ++j) v[j] = f2bf(xv[i][j]);
        *reinterpret_cast<short4v*>(&PxA[pad16(stChunk[i]) * 8 + stOff]) = v;
    }
    // issue slice-1 loads
    if (1 < nslices) {
        const float* xs = x + ((size_t)DIMC + c) * (HW * HW);
#pragma unroll
        for (int i = 0; i < 8; ++i)
            xv[i] = *reinterpret_cast<const f32x4*>(&xs[ldOff + (size_t)(i << 4) * HW]);
    }
    bar_lds();

    const float cwv = cw[(l << 5) + s31];
    // WB slot for mm1 B (Bw): global t = ks - 2*(2*half+l) + 6; slot = 14 + t - bwlo
    //   = 16 + ks - 2l for BOTH halves (bwlo absorbs the half offset).
    // WB slot for mm2 A (Ah): ks - 2*wm + 6.

    // ---------------- pipelined slice loop ----------------
    for (int s = 0; s < nslices; ++s) {
        // mm1: W = X * Bw  (A = X frags, B = Bw tiles from WB)
        f32x16 acc;
#pragma unroll
        for (int j = 0; j < 16; ++j) acc[j] = 0.0f;
#pragma unroll
        for (int ks = 0; ks < 8; ++ks) {
            const short8 a = *reinterpret_cast<const short8*>(
                &PxA[pad16(((wm << 3) + ks) * 64 + lane) * 8]);
            const short8 b = *reinterpret_cast<const short8*>(
                &WB[(((16 + ks - (l << 1)) << 6) + lane) * 8]);
            acc = __builtin_amdgcn_mfma_f32_32x32x16_bf16(a, b, acc, 0, 0, 0);
        }

        // repack W -> Py as mm2 B-frags (4 values per ds_write_b64)
#pragma unroll
        for (int q = 0; q < 4; ++q) {
            const int chunk = ((l << 3) + (wm << 1) + (q >> 1)) * 64 + s31 + ((q & 1) << 5);
            short4v v;
#pragma unroll
            for (int j = 0; j < 4; ++j) v[j] = f2bf(acc[(q << 2) + j]);
            *reinterpret_cast<short4v*>(&Py[pad16(chunk) * 8 + (hi << 2)]) = v;
        }
        bar_lds();   // A: PxA reads retired; Py visible

        // stage X(s+1); issue loads X(s+2)
        if (s + 1 < nslices) {
#pragma unroll
            for (int i = 0; i < 8; ++i) {
                short4v v;
#pragma unroll
                for (int j = 0; j < 4; ++j) v[j] = f2bf(xv[i][j]);
                *reinterpret_cast<short4v*>(&PxA[pad16(stChunk[i]) * 8 + stOff]) = v;
            }
        }
        if (s + 2 < nslices) {
            const float* xs = x + ((size_t)(s + 2) * DIMC + c) * (HW * HW);
#pragma unroll
            for (int i = 0; i < 8; ++i)
                xv[i] = *reinterpret_cast<const f32x4*>(&xs[ldOff + (size_t)(i << 4) * HW]);
        }

        // mm2: Z = Ah * W  (A = Ah tiles from WB, B = W frags from Py)
#pragma unroll
        for (int j = 0; j < 16; ++j) acc[j] = 0.0f;
#pragma unroll
        for (int ks = 0; ks < 8; ++ks) {
            const short8 a = *reinterpret_cast<const short8*>(
                &WB[(((ks - (wm << 1) + 6) << 6) + lane) * 8]);
            const short8 b = *reinterpret_cast<const short8*>(
                &Py[pad16(((l << 3) + ks) * 64 + lane) * 8]);
            acc = __builtin_amdgcn_mfma_f32_32x32x16_bf16(a, b, acc, 0, 0, 0);
        }

        // stores: consecutive lanes -> consecutive w (coalesced 128B segments)
        {
            float* zc = out + ((size_t)s * DIMC + c) * (HW * HW);
            const int w0 = (half << 6) + (l << 5) + s31;
            const int hb = (wm << 5) + (hi << 2);
#pragma unroll
            for (int r = 0; r < 16; ++r) {
                const int h = hb + (r & 3) + ((r >> 2) << 3);
                zc[(size_t)h * HW + w0] = acc[r] + cwv;
            }
        }
        bar_lds();   // B: Py reads retired; PxA(s+1) visible
    }
}

extern "C" void kernel_launch(void* const* d_in, const int* in_sizes, int n_in,
                              void* d_out, int out_size, void* d_ws, size_t ws_size,
                              hipStream_t stream) {
    const float* x  = (const float*)d_in[0];
    const float* wh = (const float*)d_in[1];
    const float* bh = (const float*)d_in[2];
    const float* ww = (const float*)d_in[3];
    const float* bw = (const float*)d_in[4];
    float* outp = (float*)d_out;

    const int nbatch = in_sizes[0] / (DIMC * HW * HW);  // = 10
    dim3 grid(DIMC * 2);
    dim3 block(512);
    hipLaunchKernelGGL(sep_conv255_mfma, grid, block, 0, stream,
                       x, wh, bh, ww, bw, outp, nbatch);
}